// Round 1
// 86.531 us; speedup vs baseline: 1.0183x; 1.0183x over previous
//
#include <hip/hip_runtime.h>

// EvalEig round 8: latency/occupancy theory. Top-5 rocprof dispatches are all
// ~45us harness poison fills (256MiB @ ~6TB/s); solve_kernel < 44.5us =>
// dur 88 ~= 45 (fixed poison) + ~40 (solve) + ~3 (final). Solve's issue model
// is ~7-10us => ~4x gap, and r5->r7 proved stores are NOT it. This round:
// halve per-thread serial depth (32 segments x 28 steps), double threads
// (393K, 6-8 waves/SIMD), trim LDS 50->36.4KB (gt as 1/r only + state aliased
// into matrix row 0) for 4 blocks/CU single-round uniform residency, and
// float4 (b128) LDS for matrices/state.

namespace {
constexpr int kNE    = 4096;
constexpr int kNCH   = kNE * 3;        // 12288 chains
constexpr int kMatch = 100;
constexpr float kC   = 3.0f / 40.0f * 0.01f;
constexpr float kK1  = 13.0f / 15.0f * 0.01f;
constexpr float kK2  = 7.0f / 60.0f * 0.01f;
constexpr int kSeg        = 32;           // segments per chain
constexpr int kCPB        = 16;           // chains per block
constexpr int kZeroBlocks = kNCH / 512;   // 24
constexpr int kInfBlocks  = kNCH / kCPB;  // 768
}

__device__ __forceinline__ float rcp_f(float x) { return __builtin_amdgcn_rcpf(x); }
__device__ __forceinline__ float rcp_nr(float x) {
    float r = __builtin_amdgcn_rcpf(x);
    return fmaf(fmaf(-x, r, 1.0f), r, r);
}

__global__ __launch_bounds__(512, 6) void solve_kernel(const float* __restrict__ energy,
                                                       float* __restrict__ out,
                                                       float* __restrict__ ws)
{
    __shared__ float gt[899];                 // 3.6 KB: 1/r table (per-l factor rebuilt via 2 fma)
    __shared__ float sM[kSeg][4][kCPB][4];    // 32 KB: [seg][matrix row][chain][col]
    float* sF = &sM[0][0][0][0];
    // row 0 of each segment slot is reused as the segment-start state (phase 2),
    // row 1 as the per-segment integral accumulators (phase 3 epilogue).

    const int bid = (int)blockIdx.x;
    const int tid = (int)threadIdx.x;
    float* uzero = out + kNCH;
    float* uinf  = out + kNCH + (size_t)kMatch * kNCH;

    if (bid < kZeroBlocks) {
        // ---------------- u_zero: outward solve, 94 steps, 1 thread/chain ----
        const int t  = bid * 512 + tid;
        const int l  = t % 3;
        const int ei = t / 3;
        const float e = energy[ei], negE = -e;
        const float ll1 = (float)(l * (l + 1));
        const float rdiv = (l == 0) ? 0.5f : ((l == 1) ? 0.25f : (1.0f/6.0f));
        float p0,p1,p2,p3,p4;
        {
            float pw[5];
            #pragma unroll
            for (int k = 0; k < 5; ++k) {
                float r = 0.1f * (float)(k + 1);
                float rl1 = (l == 0) ? r : ((l == 1) ? r*r : r*r*r);
                pw[k] = rl1 - (rl1 * r) * rdiv;
                uzero[(size_t)k * kNCH + t] = pw[k];
            }
            uzero[(size_t)5 * kNCH + t] = pw[4];
            p0=pw[0]; p1=pw[1]; p2=pw[2]; p3=pw[3]; p4=pw[4];
        }
        float acc4, acc2;
        {
            float q0=p0*p0, q1=p1*p1, q2=p2*p2, q3=p3*p3, q4=p4*p4;
            acc4 = 7.0f*q0*q0 + 32.0f*q1*q1 + 32.0f*q3*q3 + 14.0f*q4*q4 + 32.0f*q4*q4;
            acc2 = q2;
        }
        float f0, f1, f2, f3;
        {
            float i1 = rcp_f(0.2f), i2 = rcp_f(0.3f), i3 = rcp_f(0.4f), i4 = rcp_f(0.5f);
            f0 = fmaf(i1, fmaf(ll1, i1, -1.0f), negE);
            f1 = fmaf(i2, fmaf(ll1, i2, -1.0f), negE);
            f2 = fmaf(i3, fmaf(ll1, i3, -1.0f), negE);
            f3 = fmaf(i4, fmaf(ll1, i4, -1.0f), negE);
        }
        float* ptr = uzero + (size_t)6 * kNCH + t;
        #pragma unroll 4
        for (int j = 5; j <= 98; ++j) {
            float ri = rcp_f(fmaf((float)j, 0.1f, 0.1f));
            float f4 = fmaf(ri, fmaf(ll1, ri, -1.0f), negE);
            float iv = rcp_f(fmaf(-kC, f4, 1.0f));
            float a  = fmaf(kC  * f0, iv, -1.0f);
            float b  = fmaf(kK1 * f1, iv,  2.0f);
            float cc = fmaf(kK2 * f2, iv, -2.0f);
            float d  = fmaf(kK1 * f3, iv,  2.0f);
            float nw = fmaf(d, p4, fmaf(cc, p3, fmaf(b, p2, a * p1)));
            *ptr = nw; ptr += kNCH;
            float v2 = nw*nw, v4 = v2*v2;
            if (j <= 94) {
                int m = (j + 1) & 3;
                if (m == 2)      acc2 += v2;
                else if (m == 0) acc4 += 14.0f * v4;
                else             acc4 += 32.0f * v4;
            } else if (j == 95) {
                acc4 += 7.0f * v4;
            }
            f0 = f1; f1 = f2; f2 = f3; f3 = f4;
            p0 = p1; p1 = p2; p2 = p3; p3 = p4; p4 = nw;
        }
        float integ = fmaf(12.0f, acc2, acc4) * (2.0f * 0.1f / 45.0f);
        float deriv = fmaf(25.0f, p4, fmaf(-48.0f, p3, fmaf(36.0f, p2,
                      fmaf(-16.0f, p1, 3.0f * p0)))) * (1.0f / 1.2f);
        ws[2 * kNCH + t] = deriv / p4;
        ws[3 * kNCH + t] = integ / (p4 * p4);
        return;
    }

    // ---------------- u_infty: 32-segment inward solve ----------------
    for (int jj = tid; jj < 899; jj += 512)
        gt[jj] = rcp_nr(fmaf((float)jj, -0.1f, 100.0f));
    __syncthreads();

    const int b = bid - kZeroBlocks;
    const int g = tid & (kCPB - 1);        // chain within block
    const int s = tid >> 4;                // segment 0..31 (4 per wave)
    const int t = b * kCPB + g;
    const int l  = t % 3;
    const int ei = t / 3;
    const float e = energy[ei], negE = -e;
    const float ll1 = (float)(l * (l + 1));
    // seg s: jstart = 5+28s for s<=29; s=30 starts at 843 (2 dup steps with
    // s29); s=31 starts at 871.
    const int jstart = (s <= 29) ? (5 + 28 * s) : ((s == 30) ? 843 : 871);

    float ff0, ff1, ff2, ff3;
    {
        float r0 = gt[jstart - 4], r1 = gt[jstart - 3];
        float r2 = gt[jstart - 2], r3 = gt[jstart - 1];
        ff0 = fmaf(r0, fmaf(ll1, r0, -1.0f), negE);
        ff1 = fmaf(r1, fmaf(ll1, r1, -1.0f), negE);
        ff2 = fmaf(r2, fmaf(ll1, r2, -1.0f), negE);
        ff3 = fmaf(r3, fmaf(ll1, r3, -1.0f), negE);
    }
    float F0 = ff0, F1 = ff1, F2 = ff2, F3 = ff3;
    const float* gp0 = &gt[jstart];
    const float* gp = gp0;

    float ca, cb, cc_, cd;
#define COEF(FA,FB,FC,FD) \
    { float ri = *gp; gp += 1; \
      float f4 = fmaf(ri, fmaf(ll1, ri, -1.0f), negE); \
      float x  = kC * f4; \
      float iv = fmaf(x, x, x) + 1.0f; \
      ca  = fmaf(kC  * FA, iv, -1.0f); \
      cb  = fmaf(kK1 * FB, iv,  2.0f); \
      cc_ = fmaf(kK2 * FC, iv, -2.0f); \
      cd  = fmaf(kK1 * FD, iv,  2.0f); \
      FA = f4; }

#define MSTEP(FA,FB,FC,FD,RA,RB,RC,RD) \
    { COEF(FA,FB,FC,FD) \
      RA[0] = fmaf(cd,RD[0], fmaf(cc_,RC[0], fmaf(cb,RB[0], ca*RA[0]))); \
      RA[1] = fmaf(cd,RD[1], fmaf(cc_,RC[1], fmaf(cb,RB[1], ca*RA[1]))); \
      RA[2] = fmaf(cd,RD[2], fmaf(cc_,RC[2], fmaf(cb,RB[2], ca*RA[2]))); \
      RA[3] = fmaf(cd,RD[3], fmaf(cc_,RC[3], fmaf(cb,RB[3], ca*RA[3]))); }

    // ---- phase 1: companion products. s<=28,s==30: 28 steps; s==29: 26
    // steps (state for s30 needed at j=843 = 817+26, rotation offset 2);
    // s==31: no matrix.
    if (s != 31) {
        float ra[4] = {1,0,0,0}, rb[4] = {0,1,0,0}, rc[4] = {0,0,1,0}, rd[4] = {0,0,0,1};
        const int full = (s == 29) ? 6 : 7;
        for (int it = 0; it < full; ++it) {     // 4-step groups, rotation restored
            MSTEP(F0,F1,F2,F3, ra,rb,rc,rd)
            MSTEP(F1,F2,F3,F0, rb,rc,rd,ra)
            MSTEP(F2,F3,F0,F1, rc,rd,ra,rb)
            MSTEP(F3,F0,F1,F2, rd,ra,rb,rc)
        }
        if (s == 29) {                          // +2 = 26; logical order rc,rd,ra,rb
            MSTEP(F0,F1,F2,F3, ra,rb,rc,rd)
            MSTEP(F1,F2,F3,F0, rb,rc,rd,ra)
            #pragma unroll
            for (int c = 0; c < 4; ++c) {
                float t0 = ra[c]; ra[c] = rc[c]; rc[c] = t0;
                float t1 = rb[c]; rb[c] = rd[c]; rd[c] = t1;
            }
        }
        *(float4*)&sM[s][0][g][0] = make_float4(ra[0], ra[1], ra[2], ra[3]);
        *(float4*)&sM[s][1][g][0] = make_float4(rb[0], rb[1], rb[2], rb[3]);
        *(float4*)&sM[s][2][g][0] = make_float4(rc[0], rc[1], rc[2], rc[3]);
        *(float4*)&sM[s][3][g][0] = make_float4(rd[0], rd[1], rd[2], rd[3]);
    }
    __syncthreads();

    // ---- phase 2: per-chain serial combine (lanes tid 0..15). Reads each
    // segment's matrix rows, then overwrites row 0 with that segment's start
    // state (read-before-write makes the alias safe).
    if (s == 0) {
        const float se  = sqrtf(fabsf(e));
        const float rfc = (l == 0) ? 1.0f : ((l == 1) ? (1.0f/3.0f) : (1.0f/15.0f));
        const float rt1 = (l == 0) ? (1.0f/3.0f) : ((l == 1) ? (1.0f/5.0f) : (1.0f/7.0f));
        const float rt2 = (l == 0) ? (1.0f/30.0f) : ((l == 1) ? (1.0f/70.0f) : (1.0f/126.0f));
        float pw[5];
        #pragma unroll
        for (int k = 0; k < 5; ++k) {
            float rinf = 99.6f + 0.1f * (float)k;
            float x  = rinf * se;
            float xl = (l == 0) ? 1.0f : ((l == 1) ? x : x * x);
            float h  = x * x * 0.5f;
            pw[k] = rinf * (xl * rfc * (1.0f + h * rt1 + (h * h) * rt2));
        }
        uinf[(size_t)899 * kNCH + t] = pw[4];
        float st0 = pw[1], st1 = pw[2], st2 = pw[3], st3 = pw[4];
        for (int ss = 0; ss < kSeg; ++ss) {
            if (ss < kSeg - 1) {
                float4 M0 = *(const float4*)&sM[ss][0][g][0];
                float4 M1 = *(const float4*)&sM[ss][1][g][0];
                float4 M2 = *(const float4*)&sM[ss][2][g][0];
                float4 M3 = *(const float4*)&sM[ss][3][g][0];
                *(float4*)&sM[ss][0][g][0] = make_float4(st0, st1, st2, st3);
                float n0 = fmaf(M0.w,st3, fmaf(M0.z,st2, fmaf(M0.y,st1, M0.x*st0)));
                float n1 = fmaf(M1.w,st3, fmaf(M1.z,st2, fmaf(M1.y,st1, M1.x*st0)));
                float n2 = fmaf(M2.w,st3, fmaf(M2.z,st2, fmaf(M2.y,st1, M2.x*st0)));
                float n3 = fmaf(M3.w,st3, fmaf(M3.z,st2, fmaf(M3.y,st1, M3.x*st0)));
                st0 = n0; st1 = n1; st2 = n2; st3 = n3;
            } else {
                *(float4*)&sM[ss][0][g][0] = make_float4(st0, st1, st2, st3);
            }
        }
    }
    __syncthreads();

    // ---- phase 3: uniform 28-step replay, register-resident quad weights.
    // Row written = 903 - j; row%4 = (3-j)%4. j%4==1 -> acc2 (12*u^2);
    // j%4==2,0 -> 32*u^4; j%4==3 -> 14*u^4 (interior).
    float W0[4] = {0.0f, 32.0f, 14.0f, 32.0f};   // group 0 slots (jstart ≡ 1 mod 4)
    float V0[4] = {1.0f, 0.0f, 0.0f, 0.0f};
    float WR[4] = {0.0f, 32.0f, 14.0f, 32.0f};   // groups 1..6
    float VR[4] = {1.0f, 0.0f, 0.0f, 0.0f};
    if (s == 0) {        // j=5,6 -> rows 898,897 weight 0; j=7 -> row 896 = 7*u^4; j=8 -> 32
        W0[0]=0; V0[0]=0; W0[1]=0; V0[1]=0; W0[2]=7.0f; V0[2]=0; W0[3]=32.0f; V0[3]=0;
    } else if (s >= 30) { // jstart ≡ 3 mod 4: slots j≡3,0,1,2 -> {14,32,acc2,32}
        WR[0]=14.0f; VR[0]=0; WR[1]=32.0f; VR[1]=0; WR[2]=0; VR[2]=1.0f; WR[3]=32.0f; VR[3]=0;
        if (s == 30) {   // j=843,844 duplicated with s29 -> skip; j=845 -> acc2; j=846 -> 32
            W0[0]=0; W0[1]=0; W0[2]=0;     W0[3]=32.0f;
            V0[0]=0; V0[1]=0; V0[2]=1.0f;  V0[3]=0;
        } else {         // s==31, jstart=871
            W0[0]=14.0f; W0[1]=32.0f; W0[2]=0;    W0[3]=32.0f;
            V0[0]=0;     V0[1]=0;     V0[2]=1.0f; V0[3]=0;
        }
    }

    gp = gp0;
    F0 = ff0; F1 = ff1; F2 = ff2; F3 = ff3;
    float p0, p1, p2, p3;
    {
        float4 P = *(const float4*)&sM[s][0][g][0];
        p0 = P.x; p1 = P.y; p2 = P.z; p3 = P.w;
    }
    float acc4 = 0.0f, acc2 = 0.0f;
    float* ptr = uinf + (size_t)(903 - jstart) * kNCH + t;
#define RSTEPW(FA,FB,FC,FD,PA,PB,PC,PD,W,V,K) \
    { COEF(FA,FB,FC,FD) \
      float nw = fmaf(cd,PD, fmaf(cc_,PC, fmaf(cb,PB, ca*PA))); \
      PA = nw; *ptr = nw; ptr -= kNCH; \
      float v2 = nw*nw, v4 = v2*v2; \
      acc4 = fmaf(W[K], v4, acc4); \
      acc2 = fmaf(V[K], v2, acc2); }
#define GROUP(W,V) \
    RSTEPW(F0,F1,F2,F3, p0,p1,p2,p3, W,V,0) \
    RSTEPW(F1,F2,F3,F0, p1,p2,p3,p0, W,V,1) \
    RSTEPW(F2,F3,F0,F1, p2,p3,p0,p1, W,V,2) \
    RSTEPW(F3,F0,F1,F2, p3,p0,p1,p2, W,V,3)

    GROUP(W0,V0)                                   // group 0
    for (int it = 0; it < 5; ++it) { GROUP(WR,VR) }    // groups 1..5
    float h0 = p3;                                 // s==31: w894 (after 6 groups)
    GROUP(WR,VR)                                   // group 6
#undef GROUP
#undef RSTEPW

    {   // per-segment integral partials -> row-1 slots (matrices are dead)
        float2 rr; rr.x = acc4; rr.y = acc2;
        *(float2*)&sF[s * 256 + 64 + 4 * g] = rr;
    }
    __syncthreads();

    if (s == kSeg - 1) {
        float a4 = 0.0f, a2 = 0.0f;
        #pragma unroll
        for (int ss = 0; ss < kSeg; ++ss) {
            float2 rr = *(const float2*)&sF[ss * 256 + 64 + 4 * g];
            a4 += rr.x; a2 += rr.y;
        }
        // after full 28 steps: p0..p3 = w895..w898 (rotation restored)
        float h1 = p0, h2 = p1, h3 = p2, h4 = p3;
        uinf[(size_t)0 * kNCH + t] = h0;
        uinf[(size_t)1 * kNCH + t] = h1;
        uinf[(size_t)2 * kNCH + t] = h2;
        uinf[(size_t)3 * kNCH + t] = h3;
        uinf[(size_t)4 * kNCH + t] = h4;
        float q0 = h0*h0, q1 = h1*h1, q2 = h2*h2, q3 = h3*h3, q4 = h4*h4;
        a4 += 7.0f*q0*q0 + 32.0f*q1*q1 + 32.0f*q3*q3 + 14.0f*q4*q4;
        a2 += q2;
        float integ = fmaf(12.0f, a2, a4) * (2.0f * 0.1f / 45.0f);
        float deriv = fmaf(25.0f, h0, fmaf(-48.0f, h1, fmaf(36.0f, h2,
                      fmaf(-16.0f, h3, 3.0f * h4)))) * (1.0f / 1.2f);
        ws[t]        = deriv / h0;            // lfunc_out (pre energy-reversal)
        ws[kNCH + t] = integ / (h0 * h0);     // integ_out / u_infty[0]^2
    }
#undef MSTEP
#undef COEF
}

__global__ __launch_bounds__(256) void final_kernel(const float* __restrict__ energy,
                                                    const float* __restrict__ ws,
                                                    float* __restrict__ out)
{
    int t = (int)blockIdx.x * 256 + (int)threadIdx.x;
    if (t >= kNCH) return;
    int l = t % 3, ei = t / 3;
    float lf_out = ws[(kNE - 1 - ei) * 3 + l];   // energy-axis reversed
    float lf_in  = ws[2 * kNCH + t];
    float den    = ws[kNCH + t] + ws[3 * kNCH + t];
    out[t] = energy[ei] - (lf_out - lf_in) / den;
}

extern "C" void kernel_launch(void* const* d_in, const int* in_sizes, int n_in,
                              void* d_out, int out_size, void* d_ws, size_t ws_size,
                              hipStream_t stream) {
    (void)in_sizes; (void)n_in; (void)out_size; (void)ws_size;
    const float* energy = (const float*)d_in[0];
    float* out = (float*)d_out;
    float* ws  = (float*)d_ws;   // 4*12288 floats = 192 KB scratch
    solve_kernel<<<kZeroBlocks + kInfBlocks, 512, 0, stream>>>(energy, out, ws);
    final_kernel<<<kNCH / 256, 256, 0, stream>>>(energy, ws, out);
}